// Round 2
// baseline (966.721 us; speedup 1.0000x reference)
//
#include <hip/hip_runtime.h>
#include <math.h>

#define F_DIM 64
#define NUM_S 4

// ws layout:
//   float M[64*64]          : 16 KB   (M[b][f] = embed[b] . G_w[f])
//   float d2[N]             : out-degree accumulator -> rsqrt
//   int   cnt[N]            : in-degree counts (histogram)
//   int   start[N]          : exclusive-scan of cnt
//   int   cursor[N]         : scatter cursors (init = start)
//   int2  slot[E]           : {edge_id, src} sorted by dst
// total ~ 16K + 200K*4 + 4M  ~= 4.8 MB

__global__ void m_table_kernel(const float* __restrict__ embed,
                               const float* __restrict__ G_w,
                               float* __restrict__ M) {
    int b = blockIdx.x, f = threadIdx.x;
    float acc = 0.f;
    #pragma unroll
    for (int d = 0; d < 32; ++d)
        acc += embed[b * 32 + d] * G_w[f * 32 + d];
    M[b * F_DIM + f] = acc;
}

__global__ void hist_kernel(const int* __restrict__ src, const int* __restrict__ dst,
                            float* __restrict__ d2, int* __restrict__ cnt, int E) {
    int i = blockIdx.x * blockDim.x + threadIdx.x;
    if (i < E) {
        atomicAdd(&cnt[dst[i]], 1);
        atomicAdd(&d2[src[i]], 1.0f);
    }
}

__global__ void d2_transform_kernel(float* __restrict__ d2, int N) {
    int i = blockIdx.x * blockDim.x + threadIdx.x;
    if (i < N) d2[i] = 1.0f / sqrtf(fmaxf(d2[i], 1.0f));
}

// single-block exclusive scan of cnt[N] -> start, cursor
__global__ __launch_bounds__(1024) void scan_kernel(const int* __restrict__ cnt,
                                                    int* __restrict__ start,
                                                    int* __restrict__ cursor, int N) {
    __shared__ int ssum[1024];
    int tid = threadIdx.x;
    int chunk = (N + 1023) >> 10;
    int b = tid * chunk, e = min(b + chunk, N);
    int s = 0;
    for (int i = b; i < e; ++i) s += cnt[i];
    ssum[tid] = s;
    __syncthreads();
    // Hillis-Steele inclusive scan
    for (int off = 1; off < 1024; off <<= 1) {
        int v = (tid >= off) ? ssum[tid - off] : 0;
        __syncthreads();
        ssum[tid] += v;
        __syncthreads();
    }
    int off = (tid > 0) ? ssum[tid - 1] : 0;
    for (int i = b; i < e; ++i) {
        start[i] = off; cursor[i] = off;
        off += cnt[i];
    }
}

__global__ void scatter_kernel(const int* __restrict__ src, const int* __restrict__ dst,
                               int* __restrict__ cursor, int2* __restrict__ slot, int E) {
    int i = blockIdx.x * blockDim.x + threadIdx.x;
    if (i < E) {
        int p = atomicAdd(&cursor[dst[i]], 1);
        slot[p] = make_int2(i, src[i]);
    }
}

// one wave per dst node: accumulate 128-dim pre-matmul vector over its edges,
// then apply agg_w (row per lane, register-resident) + bias + d0 scaling.
__global__ __launch_bounds__(256) void node_kernel(
    const float* __restrict__ feat, const float* __restrict__ loc,
    const float* __restrict__ boundaries, const float* __restrict__ agg_w,
    const float* __restrict__ agg_b, const int* __restrict__ inter,
    const float* __restrict__ M, const float* __restrict__ d2,
    const int* __restrict__ cnt, const int* __restrict__ start,
    const int2* __restrict__ slot, float* __restrict__ out, int N) {

    __shared__ float cat[4][128];
    const int lane = threadIdx.x & 63;
    const int wid  = threadIdx.x >> 6;
    const int d    = blockIdx.x * 4 + wid;
    if (d >= N) return;

    // per-lane constants
    const float bnd  = (lane < 63) ? boundaries[lane] : 3.4e38f;
    const float bias = agg_b[lane];
    // agg_w row for this lane -> registers (128 floats)
    float ar[128];
    const float4* awv = (const float4*)(agg_w + lane * 128);
    #pragma unroll
    for (int i = 0; i < 32; ++i) ((float4*)ar)[i] = awv[i];

    const int deg  = cnt[d];
    const int base = start[d];
    const float ddx = loc[d * 3 + 0], ddy = loc[d * 3 + 1], ddz = loc[d * 3 + 2];

    float acc0 = 0.f, acc1 = 0.f, sw = 0.f;

    int2 es = (deg > 0) ? slot[base] : make_int2(0, 0);
    for (int k = 0; k < deg; ++k) {
        int2 nxt = (k + 1 < deg) ? slot[base + k + 1] : es;   // prefetch
        const int eid = es.x, s = es.y;

        const float sx = loc[s * 3 + 0], sy = loc[s * 3 + 1], sz = loc[s * 3 + 2];
        const float w  = d2[s];
        const int4 ii  = *(const int4*)(inter + eid * 4);

        // bucket of ||loc[d]-loc[s]||
        float dx = ddx - sx, dy = ddy - sy, dz = ddz - sz;
        float dist1 = sqrtf(dx * dx + dy * dy + dz * dz);
        int b1 = (int)__popcll(__ballot(bnd < dist1));
        acc0 += w * M[b1 * F_DIM + lane] * feat[s * F_DIM + lane];

        float t = 0.f;
        const int idx[4] = {ii.x, ii.y, ii.z, ii.w};
        #pragma unroll
        for (int j = 0; j < NUM_S; ++j) {
            int tj = idx[j];
            float tx = loc[tj * 3 + 0] - sx, ty = loc[tj * 3 + 1] - sy, tz = loc[tj * 3 + 2] - sz;
            float dj = sqrtf(tx * tx + ty * ty + tz * tz);
            int bj = (int)__popcll(__ballot(bnd < dj));
            t += M[bj * F_DIM + lane] * feat[tj * F_DIM + lane];
        }
        acc1 += w * 0.25f * t;
        sw += w;
        es = nxt;
    }

    // stage 128-dim accumulated cat through LDS (same-wave write->read)
    cat[wid][lane]      = acc0;
    cat[wid][64 + lane] = acc1;

    float msg = bias * sw;
    #pragma unroll
    for (int k4 = 0; k4 < 32; ++k4) {
        float4 c = ((const float4*)cat[wid])[k4];
        msg += ar[k4 * 4 + 0] * c.x;
        msg += ar[k4 * 4 + 1] * c.y;
        msg += ar[k4 * 4 + 2] * c.z;
        msg += ar[k4 * 4 + 3] * c.w;
    }

    const float d0v = 1.0f / sqrtf(fmaxf((float)deg, 1.0f));
    out[d * F_DIM + lane] = d0v * msg;
}

extern "C" void kernel_launch(void* const* d_in, const int* in_sizes, int n_in,
                              void* d_out, int out_size, void* d_ws, size_t ws_size,
                              hipStream_t stream) {
    const float* feat       = (const float*)d_in[0];
    const float* loc        = (const float*)d_in[1];
    const float* boundaries = (const float*)d_in[2];
    const float* embed      = (const float*)d_in[3];
    const float* G_w        = (const float*)d_in[4];
    const float* agg_w      = (const float*)d_in[5];
    const float* agg_b      = (const float*)d_in[6];
    const int*   src        = (const int*)d_in[7];
    const int*   dst        = (const int*)d_in[8];
    const int*   inter      = (const int*)d_in[9];

    const int N = in_sizes[0] / F_DIM;   // 50000
    const int E = in_sizes[7];           // 500000

    float* M      = (float*)d_ws;
    float* d2     = M + 64 * F_DIM;
    int*   cnt    = (int*)(d2 + N);
    int*   start  = cnt + N;
    int*   cursor = start + N;
    int2*  slot   = (int2*)(cursor + N);
    float* out    = (float*)d_out;

    // zero d2 (N floats) + cnt (N ints) in one shot (contiguous)
    hipMemsetAsync(d2, 0, (size_t)2 * N * sizeof(float), stream);

    m_table_kernel<<<64, F_DIM, 0, stream>>>(embed, G_w, M);
    hist_kernel<<<(E + 255) / 256, 256, 0, stream>>>(src, dst, d2, cnt, E);
    d2_transform_kernel<<<(N + 255) / 256, 256, 0, stream>>>(d2, N);
    scan_kernel<<<1, 1024, 0, stream>>>(cnt, start, cursor, N);
    scatter_kernel<<<(E + 255) / 256, 256, 0, stream>>>(src, dst, cursor, slot, E);
    node_kernel<<<(N + 3) / 4, 256, 0, stream>>>(feat, loc, boundaries, agg_w, agg_b,
                                                 inter, M, d2, cnt, start, slot, out, N);
}

// Round 3
// 289.456 us; speedup vs baseline: 3.3398x; 3.3398x over previous
//
#include <hip/hip_runtime.h>
#include <math.h>

#define F_DIM 64

// ---------------- tiny prep kernels ----------------

__global__ void m_table_kernel(const float* __restrict__ embed,
                               const float* __restrict__ G_w,
                               float* __restrict__ M) {
    int b = blockIdx.x, f = threadIdx.x;
    float acc = 0.f;
    #pragma unroll
    for (int d = 0; d < 32; ++d)
        acc += embed[b * 32 + d] * G_w[f * 32 + d];
    M[b * F_DIM + f] = acc;
}

__global__ void wt_kernel(const float* __restrict__ agg_w, float* __restrict__ Wt) {
    // Wt[k][f] = agg_w[f][k],  k<128 (blockIdx), f<64 (threadIdx)
    Wt[blockIdx.x * 64 + threadIdx.x] = agg_w[threadIdx.x * 128 + blockIdx.x];
}

__global__ void hist_kernel(const int* __restrict__ src, const int* __restrict__ dst,
                            float* __restrict__ d2, int* __restrict__ cnt, int E) {
    int i = blockIdx.x * blockDim.x + threadIdx.x;
    if (i < E) {
        atomicAdd(&cnt[dst[i]], 1);
        atomicAdd(&d2[src[i]], 1.0f);
    }
}

__global__ void d2_transform_kernel(float* __restrict__ d2, int N) {
    int i = blockIdx.x * blockDim.x + threadIdx.x;
    if (i < N) d2[i] = 1.0f / sqrtf(fmaxf(d2[i], 1.0f));
}

// ---------------- parallel exclusive scan of cnt[N] ----------------

__global__ __launch_bounds__(1024) void scan_block_kernel(const int* __restrict__ cnt,
                                                          int* __restrict__ start,
                                                          int* __restrict__ part, int N) {
    __shared__ int sh[1024];
    int t = threadIdx.x, i = blockIdx.x * 1024 + t;
    int v = (i < N) ? cnt[i] : 0;
    sh[t] = v;
    __syncthreads();
    for (int off = 1; off < 1024; off <<= 1) {
        int y = (t >= off) ? sh[t - off] : 0;
        __syncthreads();
        sh[t] += y;
        __syncthreads();
    }
    if (i < N) start[i] = sh[t] - v;            // block-local exclusive
    if (t == 1023) part[blockIdx.x] = sh[1023]; // block total
}

__global__ void scan_part_kernel(const int* __restrict__ part, int* __restrict__ partoff, int nb) {
    int lane = threadIdx.x;                     // 64 threads, nb <= 64
    int v = (lane < nb) ? part[lane] : 0;
    int x = v;
    #pragma unroll
    for (int off = 1; off < 64; off <<= 1) {
        int y = __shfl_up(x, off);
        if (lane >= off) x += y;
    }
    if (lane < nb) partoff[lane] = x - v;       // exclusive
}

__global__ __launch_bounds__(1024) void scan_fix_kernel(int* __restrict__ start,
                                                        int* __restrict__ cursor,
                                                        const int* __restrict__ partoff, int N) {
    int i = blockIdx.x * 1024 + threadIdx.x;
    if (i < N) {
        int s = start[i] + partoff[blockIdx.x];
        start[i] = s;
        cursor[i] = s;
    }
}

// ---------------- phase 1: thread-per-edge bucket + scatter fat record ----------------
// record (8 ints, 32 B): {src, i0, i1, i2, i3, bucket_pack(5x6 bits), bitcast(w), 0}

__global__ __launch_bounds__(256) void bucket_scatter_kernel(
    const float* __restrict__ loc, const float* __restrict__ boundaries,
    const float* __restrict__ d2, const int* __restrict__ src,
    const int* __restrict__ dst, const int* __restrict__ inter,
    int* __restrict__ cursor, int* __restrict__ rec, int E) {

    __shared__ float bl[64];
    if (threadIdx.x < 64)
        bl[threadIdx.x] = (threadIdx.x < 63) ? boundaries[threadIdx.x] : 3.4e38f;
    __syncthreads();

    int i = blockIdx.x * 256 + threadIdx.x;
    if (i >= E) return;

    const int s = src[i], d = dst[i];
    const int4 ii = *(const int4*)(inter + (size_t)i * 4);
    const float sx = loc[3 * s], sy = loc[3 * s + 1], sz = loc[3 * s + 2];

    float dist[5];
    {
        float dx = loc[3 * d] - sx, dy = loc[3 * d + 1] - sy, dz = loc[3 * d + 2] - sz;
        dist[0] = sqrtf(dx * dx + dy * dy + dz * dz);
    }
    const int id4[4] = {ii.x, ii.y, ii.z, ii.w};
    #pragma unroll
    for (int j = 0; j < 4; ++j) {
        int t = id4[j];
        float dx = loc[3 * t] - sx, dy = loc[3 * t + 1] - sy, dz = loc[3 * t + 2] - sz;
        dist[1 + j] = sqrtf(dx * dx + dy * dy + dz * dz);
    }

    unsigned pack = 0;
    #pragma unroll
    for (int q = 0; q < 5; ++q) {
        // lower_bound over bl[0..62]: count of boundaries < dist
        int lo = 0, hi = 63;
        #pragma unroll
        for (int it = 0; it < 6; ++it) {
            int mid = (lo + hi) >> 1;
            if (bl[mid] < dist[q]) lo = mid + 1; else hi = mid;
        }
        pack |= ((unsigned)lo) << (6 * q);
    }

    const float w = d2[s];
    const int p = atomicAdd(&cursor[d], 1);
    int* r = rec + (size_t)p * 8;
    *(int4*)(r)     = make_int4(s, ii.x, ii.y, ii.z);
    *(int4*)(r + 4) = make_int4(ii.w, (int)pack, __float_as_int(w), 0);
}

// ---------------- phase 2: wave-per-node accumulate + epilogue matvec ----------------

__global__ __launch_bounds__(256) void node_kernel(
    const float* __restrict__ feat, const float* __restrict__ Wt,
    const float* __restrict__ agg_b, const float* __restrict__ M,
    const int* __restrict__ cnt, const int* __restrict__ start,
    const int* __restrict__ rec, float* __restrict__ out, int N) {

    __shared__ float Ms[4096];      // M table, 16 KB
    __shared__ float cat[4][128];

    // cooperative M load (1024 float4 / 256 threads)
    #pragma unroll
    for (int i = 0; i < 4; ++i)
        ((float4*)Ms)[threadIdx.x + 256 * i] = ((const float4*)M)[threadIdx.x + 256 * i];
    __syncthreads();

    const int lane = threadIdx.x & 63;
    const int wid  = threadIdx.x >> 6;
    const int d    = blockIdx.x * 4 + wid;
    if (d >= N) return;

    const int deg  = cnt[d];
    const int base = start[d];
    const int* rp  = rec + (size_t)base * 8;

    float acc0 = 0.f, acc1 = 0.f, sw = 0.f;

    #pragma unroll 2
    for (int k = 0; k < deg; ++k) {
        const int4 r0 = *(const int4*)(rp + (size_t)k * 8);
        const int4 r1 = *(const int4*)(rp + (size_t)k * 8 + 4);
        const int s = r0.x;
        const unsigned pk = (unsigned)r1.y;
        const float w = __int_as_float(r1.z);

        // all independent: 5 coalesced feat gathers + 5 LDS reads
        const float fs = feat[(size_t)s * 64 + lane];
        const float f0 = feat[(size_t)r0.y * 64 + lane];
        const float f1 = feat[(size_t)r0.z * 64 + lane];
        const float f2 = feat[(size_t)r0.w * 64 + lane];
        const float f3 = feat[(size_t)r1.x * 64 + lane];
        const float m0 = Ms[(pk & 63u) * 64 + lane];
        const float m1 = Ms[((pk >> 6) & 63u) * 64 + lane];
        const float m2 = Ms[((pk >> 12) & 63u) * 64 + lane];
        const float m3 = Ms[((pk >> 18) & 63u) * 64 + lane];
        const float m4 = Ms[((pk >> 24) & 63u) * 64 + lane];

        acc0 += w * m0 * fs;
        float t = m1 * f0 + m2 * f1 + m3 * f2 + m4 * f3;
        acc1 += w * 0.25f * t;
        sw += w;
    }

    // epilogue: msg[lane] = bias*sw + sum_k Wt[k][lane] * cat[k]
    cat[wid][lane]      = acc0;
    cat[wid][64 + lane] = acc1;

    float msg = agg_b[lane] * sw;
    #pragma unroll 8
    for (int k = 0; k < 128; ++k)
        msg += Wt[k * 64 + lane] * cat[wid][k];   // coalesced + LDS broadcast

    const float d0v = rsqrtf(fmaxf((float)deg, 1.0f));
    out[(size_t)d * 64 + lane] = d0v * msg;
}

// ---------------- launch ----------------

extern "C" void kernel_launch(void* const* d_in, const int* in_sizes, int n_in,
                              void* d_out, int out_size, void* d_ws, size_t ws_size,
                              hipStream_t stream) {
    const float* feat       = (const float*)d_in[0];
    const float* loc        = (const float*)d_in[1];
    const float* boundaries = (const float*)d_in[2];
    const float* embed      = (const float*)d_in[3];
    const float* G_w        = (const float*)d_in[4];
    const float* agg_w      = (const float*)d_in[5];
    const float* agg_b      = (const float*)d_in[6];
    const int*   src        = (const int*)d_in[7];
    const int*   dst        = (const int*)d_in[8];
    const int*   inter      = (const int*)d_in[9];

    const int N = in_sizes[0] / F_DIM;   // 50000
    const int E = in_sizes[7];           // 500000

    float* M       = (float*)d_ws;            // 4096 f
    float* Wt      = M + 4096;                // 8192 f
    float* d2      = Wt + 8192;               // N f
    int*   cnt     = (int*)(d2 + N);          // N
    int*   start   = cnt + N;                 // N
    int*   cursor  = start + N;               // N
    int*   part    = cursor + N;              // 64
    int*   partoff = part + 64;               // 64
    int*   rec     = partoff + 64;            // E*8  (16 MB)
    float* out     = (float*)d_out;

    const int nb = (N + 1023) / 1024;         // scan blocks (49)

    // zero d2 (N floats) + cnt (N ints): contiguous
    hipMemsetAsync(d2, 0, (size_t)2 * N * sizeof(float), stream);

    m_table_kernel<<<64, 64, 0, stream>>>(embed, G_w, M);
    wt_kernel<<<128, 64, 0, stream>>>(agg_w, Wt);
    hist_kernel<<<(E + 255) / 256, 256, 0, stream>>>(src, dst, d2, cnt, E);
    d2_transform_kernel<<<(N + 255) / 256, 256, 0, stream>>>(d2, N);
    scan_block_kernel<<<nb, 1024, 0, stream>>>(cnt, start, part, N);
    scan_part_kernel<<<1, 64, 0, stream>>>(part, partoff, nb);
    scan_fix_kernel<<<nb, 1024, 0, stream>>>(start, cursor, partoff, N);
    bucket_scatter_kernel<<<(E + 255) / 256, 256, 0, stream>>>(loc, boundaries, d2, src, dst,
                                                               inter, cursor, rec, E);
    node_kernel<<<(N + 3) / 4, 256, 0, stream>>>(feat, Wt, agg_b, M, cnt, start, rec, out, N);
}

// Round 4
// 289.333 us; speedup vs baseline: 3.3412x; 1.0004x over previous
//
#include <hip/hip_runtime.h>
#include <math.h>

#define F_DIM 64
#define LUTN 1024
#define LUTSCALE 512.0f   // cells of width 1/512 over [0, 2)

// ---------------- prep kernels ----------------

__global__ void m_table_kernel(const float* __restrict__ embed,
                               const float* __restrict__ G_w,
                               float* __restrict__ M) {
    int b = blockIdx.x, f = threadIdx.x;
    float acc = 0.f;
    #pragma unroll
    for (int d = 0; d < 32; ++d)
        acc += embed[b * 32 + d] * G_w[f * 32 + d];
    M[b * F_DIM + f] = acc;
}

__global__ __launch_bounds__(1024) void lut_kernel(const float* __restrict__ boundaries,
                                                   int* __restrict__ lut) {
    int i = threadIdx.x;                       // one block of 1024
    float left = (float)i * (1.0f / LUTSCALE);
    int c = 0;
    for (int j = 0; j < 63; ++j) c += (boundaries[j] < left) ? 1 : 0;
    lut[i] = c;
}

__global__ void hist_kernel(const int* __restrict__ src, const int* __restrict__ dst,
                            float* __restrict__ d2, int* __restrict__ cnt, int E) {
    int i = blockIdx.x * blockDim.x + threadIdx.x;
    if (i < E) {
        atomicAdd(&cnt[dst[i]], 1);
        atomicAdd(&d2[src[i]], 1.0f);
    }
}

__global__ void d2_transform_kernel(float* __restrict__ d2, int N) {
    int i = blockIdx.x * blockDim.x + threadIdx.x;
    if (i < N) d2[i] = 1.0f / sqrtf(fmaxf(d2[i], 1.0f));
}

// ---------------- parallel exclusive scan (shfl-based) ----------------

__global__ __launch_bounds__(1024) void scan_block_kernel(const int* __restrict__ cnt,
                                                          int* __restrict__ start,
                                                          int* __restrict__ part, int N) {
    __shared__ int wsum[16];
    const int t = threadIdx.x, lane = t & 63, wv = t >> 6;
    const int i = blockIdx.x * 1024 + t;
    int v = (i < N) ? cnt[i] : 0;
    int x = v;
    #pragma unroll
    for (int off = 1; off < 64; off <<= 1) {
        int y = __shfl_up(x, off);
        if (lane >= off) x += y;
    }
    if (lane == 63) wsum[wv] = x;
    __syncthreads();
    if (t < 16) {
        int w = wsum[t], xx = w;
        #pragma unroll
        for (int off = 1; off < 16; off <<= 1) {
            int y = __shfl_up(xx, off);
            if (t >= off) xx += y;
        }
        wsum[t] = xx - w;   // exclusive wave offsets
    }
    __syncthreads();
    int incl = x + wsum[wv];
    if (i < N) start[i] = incl - v;
    if (t == 1023) part[blockIdx.x] = incl;
}

__global__ void scan_part_kernel(const int* __restrict__ part, int* __restrict__ partoff, int nb) {
    int lane = threadIdx.x;                    // 64 threads, nb <= 64
    int v = (lane < nb) ? part[lane] : 0;
    int x = v;
    #pragma unroll
    for (int off = 1; off < 64; off <<= 1) {
        int y = __shfl_up(x, off);
        if (lane >= off) x += y;
    }
    if (lane < nb) partoff[lane] = x - v;
}

__global__ __launch_bounds__(1024) void scan_fix_kernel(int* __restrict__ start,
                                                        int* __restrict__ cursor,
                                                        const int* __restrict__ partoff, int N) {
    int i = blockIdx.x * 1024 + threadIdx.x;
    if (i < N) {
        int s = start[i] + partoff[blockIdx.x];
        start[i] = s;
        cursor[i] = s;
    }
}

// ---------------- phase 1: bucket via LUT + scatter fat record ----------------
// record (8 ints, 32 B): {src, i0, i1, i2, i3, pack(5x6 bits), bitcast(w), 0}

__global__ __launch_bounds__(256) void bucket_scatter_kernel(
    const float* __restrict__ loc, const float* __restrict__ boundaries,
    const int* __restrict__ lut, const float* __restrict__ d2,
    const int* __restrict__ src, const int* __restrict__ dst,
    const int* __restrict__ inter, int* __restrict__ cursor,
    int* __restrict__ rec, int E) {

    __shared__ int lut_s[LUTN];
    __shared__ float bl[64];
    ((int4*)lut_s)[threadIdx.x] = ((const int4*)lut)[threadIdx.x];   // 256 * 16B = 4KB
    if (threadIdx.x < 64)
        bl[threadIdx.x] = (threadIdx.x < 63) ? boundaries[threadIdx.x] : 3.4e38f;
    __syncthreads();

    int i = blockIdx.x * 256 + threadIdx.x;
    if (i >= E) return;

    const int s = src[i], d = dst[i];
    const int4 ii = *(const int4*)(inter + (size_t)i * 4);
    const float sx = loc[3 * s], sy = loc[3 * s + 1], sz = loc[3 * s + 2];

    float dist[5];
    {
        float dx = loc[3 * d] - sx, dy = loc[3 * d + 1] - sy, dz = loc[3 * d + 2] - sz;
        dist[0] = sqrtf(dx * dx + dy * dy + dz * dz);
    }
    const int id4[4] = {ii.x, ii.y, ii.z, ii.w};
    #pragma unroll
    for (int j = 0; j < 4; ++j) {
        int t = id4[j];
        float dx = loc[3 * t] - sx, dy = loc[3 * t + 1] - sy, dz = loc[3 * t + 2] - sz;
        dist[1 + j] = sqrtf(dx * dx + dy * dy + dz * dz);
    }

    unsigned pack = 0;
    #pragma unroll
    for (int q = 0; q < 5; ++q) {
        float dq = dist[q];
        int cell = (int)(dq * LUTSCALE);
        cell = (cell > LUTN - 1) ? (LUTN - 1) : cell;
        int b = lut_s[cell];
        while (b < 63 && bl[b] < dq) ++b;        // fix up (expected ~0.06 iters)
        while (b > 0 && bl[b - 1] >= dq) --b;    // fix down (sub-ulp guard)
        pack |= ((unsigned)b) << (6 * q);
    }

    const float w = d2[s];
    const int p = atomicAdd(&cursor[d], 1);
    int* r = rec + (size_t)p * 8;
    *(int4*)(r)     = make_int4(s, ii.x, ii.y, ii.z);
    *(int4*)(r + 4) = make_int4(ii.w, (int)pack, __float_as_int(w), 0);
}

// ---------------- phase 2: wave-per-node gather + accumulate (no epilogue) ----------------

__global__ __launch_bounds__(256) void node_kernel(
    const float* __restrict__ feat, const float* __restrict__ M,
    const int* __restrict__ cnt, const int* __restrict__ start,
    const int* __restrict__ rec, float* __restrict__ cat,
    float* __restrict__ swb, int N) {

    __shared__ float Ms[4096];      // 16 KB
    #pragma unroll
    for (int i = 0; i < 4; ++i)
        ((float4*)Ms)[threadIdx.x + 256 * i] = ((const float4*)M)[threadIdx.x + 256 * i];
    __syncthreads();

    const int lane = threadIdx.x & 63;
    const int wid  = threadIdx.x >> 6;
    const int d    = blockIdx.x * 4 + wid;
    if (d >= N) return;

    // wave-uniform scalars -> SMEM path for rec
    const int deg  = __builtin_amdgcn_readfirstlane(cnt[d]);
    const int base = __builtin_amdgcn_readfirstlane(start[d]);
    const int* rp  = rec + (size_t)base * 8;

    float acc0 = 0.f, acc1 = 0.f, sw = 0.f;

    #pragma unroll 4
    for (int k = 0; k < deg; ++k) {
        const int s  = rp[k * 8 + 0];
        const int i0 = rp[k * 8 + 1];
        const int i1 = rp[k * 8 + 2];
        const int i2 = rp[k * 8 + 3];
        const int i3 = rp[k * 8 + 4];
        const unsigned pk = (unsigned)rp[k * 8 + 5];
        const float w = __int_as_float(rp[k * 8 + 6]);

        const float fs = feat[(size_t)s  * 64 + lane];
        const float f0 = feat[(size_t)i0 * 64 + lane];
        const float f1 = feat[(size_t)i1 * 64 + lane];
        const float f2 = feat[(size_t)i2 * 64 + lane];
        const float f3 = feat[(size_t)i3 * 64 + lane];
        const float m0 = Ms[(pk & 63u) * 64 + lane];
        const float m1 = Ms[((pk >> 6) & 63u) * 64 + lane];
        const float m2 = Ms[((pk >> 12) & 63u) * 64 + lane];
        const float m3 = Ms[((pk >> 18) & 63u) * 64 + lane];
        const float m4 = Ms[((pk >> 24) & 63u) * 64 + lane];

        acc0 = fmaf(m0 * fs, w, acc0);
        float t = m1 * f0 + m2 * f1 + m3 * f2 + m4 * f3;
        acc1 = fmaf(0.25f * t, w, acc1);
        sw += w;
    }

    cat[(size_t)d * 128 + lane]      = acc0;
    cat[(size_t)d * 128 + 64 + lane] = acc1;
    if (lane == 0) swb[d] = sw;
}

// ---------------- phase 3: epilogue GEMM  out = d0 * (cat @ agg_w^T + bias*sw) ----------------

__global__ __launch_bounds__(256) void epilogue_kernel(
    const float* __restrict__ cat, const float* __restrict__ agg_w,
    const float* __restrict__ agg_b, const float* __restrict__ swb,
    const int* __restrict__ cnt, float* __restrict__ out, int N) {

    const int lane = threadIdx.x & 63;
    const int wid  = threadIdx.x >> 6;

    // lane f holds agg_w[f][0..127] in registers (amortized over grid-stride)
    float4 aw[32];
    const float4* awp = (const float4*)(agg_w + (size_t)lane * 128);
    #pragma unroll
    for (int i = 0; i < 32; ++i) aw[i] = awp[i];
    const float bias = agg_b[lane];

    const int gw = blockIdx.x * 4 + wid;
    const int stride = gridDim.x * 4;

    for (int d0i = gw; d0i < N; d0i += stride) {
        const int du = __builtin_amdgcn_readfirstlane(d0i);
        const float* cp = cat + (size_t)du * 128;     // uniform -> s_load path
        float acc = bias * swb[du];
        #pragma unroll
        for (int k4 = 0; k4 < 32; ++k4) {
            float4 c = ((const float4*)cp)[k4];
            acc = fmaf(aw[k4].x, c.x, acc);
            acc = fmaf(aw[k4].y, c.y, acc);
            acc = fmaf(aw[k4].z, c.z, acc);
            acc = fmaf(aw[k4].w, c.w, acc);
        }
        const float d0v = rsqrtf(fmaxf((float)cnt[du], 1.0f));
        out[(size_t)du * 64 + lane] = d0v * acc;
    }
}

// ---------------- launch ----------------

extern "C" void kernel_launch(void* const* d_in, const int* in_sizes, int n_in,
                              void* d_out, int out_size, void* d_ws, size_t ws_size,
                              hipStream_t stream) {
    const float* feat       = (const float*)d_in[0];
    const float* loc        = (const float*)d_in[1];
    const float* boundaries = (const float*)d_in[2];
    const float* embed      = (const float*)d_in[3];
    const float* G_w        = (const float*)d_in[4];
    const float* agg_w      = (const float*)d_in[5];
    const float* agg_b      = (const float*)d_in[6];
    const int*   src        = (const int*)d_in[7];
    const int*   dst        = (const int*)d_in[8];
    const int*   inter      = (const int*)d_in[9];

    const int N = in_sizes[0] / F_DIM;   // 50000
    const int E = in_sizes[7];           // 500000

    float* M       = (float*)d_ws;             // 4096 f
    int*   lut     = (int*)(M + 4096);         // 1024
    float* d2      = (float*)(lut + LUTN);     // N
    int*   cnt     = (int*)(d2 + N);           // N
    int*   start   = cnt + N;                  // N
    int*   cursor  = start + N;                // N
    int*   part    = cursor + N;               // 64
    int*   partoff = part + 64;                // 64
    int*   rec     = partoff + 64;             // E*8 ints (16 MB)
    float* cat     = (float*)(rec + (size_t)E * 8);   // N*128 f (25.6 MB)
    float* swb     = cat + (size_t)N * 128;    // N
    float* out     = (float*)d_out;

    const int nb = (N + 1023) / 1024;          // 49

    hipMemsetAsync(d2, 0, (size_t)2 * N * sizeof(float), stream);   // d2 + cnt

    m_table_kernel<<<64, 64, 0, stream>>>(embed, G_w, M);
    lut_kernel<<<1, 1024, 0, stream>>>(boundaries, lut);
    hist_kernel<<<(E + 255) / 256, 256, 0, stream>>>(src, dst, d2, cnt, E);
    d2_transform_kernel<<<(N + 255) / 256, 256, 0, stream>>>(d2, N);
    scan_block_kernel<<<nb, 1024, 0, stream>>>(cnt, start, part, N);
    scan_part_kernel<<<1, 64, 0, stream>>>(part, partoff, nb);
    scan_fix_kernel<<<nb, 1024, 0, stream>>>(start, cursor, partoff, N);
    bucket_scatter_kernel<<<(E + 255) / 256, 256, 0, stream>>>(loc, boundaries, lut, d2,
                                                               src, dst, inter, cursor, rec, E);
    node_kernel<<<(N + 3) / 4, 256, 0, stream>>>(feat, M, cnt, start, rec, cat, swb, N);
    epilogue_kernel<<<768, 256, 0, stream>>>(cat, agg_w, agg_b, swb, cnt, out, N);
}